// Round 1
// baseline (921.916 us; speedup 1.0000x reference)
//
#include <hip/hip_runtime.h>
#include <stdint.h>

#define BATCH 16384
#define IN_DIM 1024
#define HDIM 4096

typedef __bf16 bf16x8 __attribute__((ext_vector_type(8)));
typedef short short8 __attribute__((ext_vector_type(8)));
typedef float f32x4 __attribute__((ext_vector_type(4)));

typedef const __attribute__((address_space(1))) void* gas_ptr;
typedef __attribute__((address_space(3))) void* las_ptr;

__device__ __forceinline__ unsigned short f2bf(float f) {
  uint32_t u = __builtin_bit_cast(uint32_t, f);
  u += 0x7fffu + ((u >> 16) & 1u);
  return (unsigned short)(u >> 16);
}

__device__ __forceinline__ void async_copy16(const void* g, void* l) {
  __builtin_amdgcn_global_load_lds((gas_ptr)g, (las_ptr)l, 16, 0, 0);
}

// ---------------- small prep kernels ----------------

__global__ void cvt_f32_bf16_kernel(const float* __restrict__ in,
                                    unsigned short* __restrict__ out, int n4) {
  int i = blockIdx.x * blockDim.x + threadIdx.x;
  if (i < n4) {
    const float4 v = ((const float4*)in)[i];
    ushort4 o;
    o.x = f2bf(v.x); o.y = f2bf(v.y); o.z = f2bf(v.z); o.w = f2bf(v.w);
    ((ushort4*)out)[i] = o;
  }
}

__global__ void cvt_i32_bf16_kernel(const int* __restrict__ in,
                                    unsigned short* __restrict__ out, int n4) {
  int i = blockIdx.x * blockDim.x + threadIdx.x;
  if (i < n4) {
    const int4 v = ((const int4*)in)[i];
    ushort4 o;
    o.x = f2bf((float)v.x); o.y = f2bf((float)v.y);
    o.z = f2bf((float)v.z); o.w = f2bf((float)v.w);
    ((ushort4*)out)[i] = o;
  }
}

__global__ void scale_kernel(const float* __restrict__ ls, float* __restrict__ s, int n) {
  int i = blockIdx.x * blockDim.x + threadIdx.x;
  if (i < n) {
    float l = ls[i];
    float sp = (l > 20.0f) ? l : log1pf(expf(l));
    s[i] = fmaxf(sp, 1e-4f);
  }
}

__global__ void init_out_kernel(float* __restrict__ out, const float* __restrict__ b_out, int n) {
  int i = blockIdx.x * blockDim.x + threadIdx.x;
  if (i < n) out[i] = b_out[0];
}

// ---------------- MFMA GEMM: C[m,n] = sum_k A[m,k]*B[n,k] ----------------
// A: [M][K] bf16 row-major, B: [N][K] bf16 row-major (B^T-input layout).
// 128x128 block tile, 4 waves (2x2), each wave 64x64 via 4x4 of 16x16x32 MFMA.
// global_load_lds width=16 staging; XOR k-chunk swizzle to kill 8-way LDS
// bank conflicts on ds_read_b128 (2-way is free per m136).
// Epilogue: v = clip(acc*scale[col]+bias[col], -1, 1).
//   FUSE=false: store v as bf16 into Hout[M][HDIM].
//   FUSE=true : out[row] += sum_col v * w_out[col]  (16-lane shuffle reduce + atomicAdd)

template <int K, bool FUSE>
__global__ __launch_bounds__(256, 2)
void gemm_kernel(const unsigned short* __restrict__ A,
                 const unsigned short* __restrict__ B,
                 const float* __restrict__ scale,
                 const float* __restrict__ bias,
                 unsigned short* __restrict__ Hout,
                 const float* __restrict__ w_out,
                 float* __restrict__ out) {
  __shared__ unsigned short As[128 * 32];
  __shared__ unsigned short Bs[128 * 32];

  const int tid = threadIdx.x;
  const int wave = tid >> 6;
  const int lane = tid & 63;
  const int lane15 = lane & 15;
  const int quad = lane >> 4;
  const int wm = wave >> 1;
  const int wn = wave & 1;
  const int row0 = blockIdx.y * 128;
  const int col0 = blockIdx.x * 128;

  f32x4 acc[4][4];
  const f32x4 zero = {0.0f, 0.0f, 0.0f, 0.0f};
#pragma unroll
  for (int i = 0; i < 4; ++i)
#pragma unroll
    for (int j = 0; j < 4; ++j) acc[i][j] = zero;

  const unsigned short* Ab = A + (size_t)row0 * K;
  const unsigned short* Bb = B + (size_t)col0 * K;

  for (int k0 = 0; k0 < K; k0 += 32) {
    __syncthreads();
    // stage A tile (128x32 bf16 = 8 KB) and B tile; 256 thr * 16 B * 2 rounds each.
    // LDS slot c holds global chunk (row=c>>2, kchunk=(c&3)^((row>>2)&3)).
#pragma unroll
    for (int r = 0; r < 2; ++r) {
      const int c = r * 256 + tid;
      const int rw = c >> 2;
      const int kc = (c & 3) ^ ((rw >> 2) & 3);
      async_copy16(Ab + rw * K + k0 + kc * 8, &As[(r * 256 + wave * 64) * 8]);
      async_copy16(Bb + rw * K + k0 + kc * 8, &Bs[(r * 256 + wave * 64) * 8]);
    }
    __syncthreads();

    bf16x8 aF[4], bF[4];
#pragma unroll
    for (int i = 0; i < 4; ++i) {
      const int ar = wm * 64 + i * 16 + lane15;
      const int sk = quad ^ ((ar >> 2) & 3);
      aF[i] = __builtin_bit_cast(bf16x8, *(const short8*)&As[ar * 32 + sk * 8]);
    }
#pragma unroll
    for (int j = 0; j < 4; ++j) {
      const int br = wn * 64 + j * 16 + lane15;
      const int sk = quad ^ ((br >> 2) & 3);
      bF[j] = __builtin_bit_cast(bf16x8, *(const short8*)&Bs[br * 32 + sk * 8]);
    }
#pragma unroll
    for (int i = 0; i < 4; ++i)
#pragma unroll
      for (int j = 0; j < 4; ++j)
        acc[i][j] = __builtin_amdgcn_mfma_f32_16x16x32_bf16(aF[i], bF[j], acc[i][j], 0, 0, 0);
  }

  // epilogue. C/D layout (16x16x32): col = lane&15, row = quad*4 + reg.
  if constexpr (!FUSE) {
#pragma unroll
    for (int j = 0; j < 4; ++j) {
      const int col = col0 + wn * 64 + j * 16 + lane15;
      const float sc = scale[col];
      const float bs = bias[col];
#pragma unroll
      for (int i = 0; i < 4; ++i) {
        const int rbase = row0 + wm * 64 + i * 16 + quad * 4;
#pragma unroll
        for (int r = 0; r < 4; ++r) {
          float v = fminf(fmaxf(acc[i][j][r] * sc + bs, -1.0f), 1.0f);
          Hout[(size_t)(rbase + r) * HDIM + col] = f2bf(v);
        }
      }
    }
  } else {
    float rs[4][4];
#pragma unroll
    for (int i = 0; i < 4; ++i)
#pragma unroll
      for (int r = 0; r < 4; ++r) rs[i][r] = 0.0f;
#pragma unroll
    for (int j = 0; j < 4; ++j) {
      const int col = col0 + wn * 64 + j * 16 + lane15;
      const float sc = scale[col];
      const float bs = bias[col];
      const float w = w_out[col];
#pragma unroll
      for (int i = 0; i < 4; ++i)
#pragma unroll
        for (int r = 0; r < 4; ++r) {
          float v = fminf(fmaxf(acc[i][j][r] * sc + bs, -1.0f), 1.0f);
          rs[i][r] += v * w;
        }
    }
    // reduce over the 16 lanes (lane15) sharing each (quad, r) row
#pragma unroll
    for (int off = 1; off < 16; off <<= 1)
#pragma unroll
      for (int i = 0; i < 4; ++i)
#pragma unroll
        for (int r = 0; r < 4; ++r)
          rs[i][r] += __shfl_xor(rs[i][r], off, 64);
    if (lane15 == 0) {
#pragma unroll
      for (int i = 0; i < 4; ++i) {
        const int rbase = row0 + wm * 64 + i * 16 + quad * 4;
#pragma unroll
        for (int r = 0; r < 4; ++r)
          atomicAdd(&out[rbase + r], rs[i][r]);
      }
    }
  }
}

// ---------------- launch ----------------

extern "C" void kernel_launch(void* const* d_in, const int* in_sizes, int n_in,
                              void* d_out, int out_size, void* d_ws, size_t ws_size,
                              hipStream_t stream) {
  (void)in_sizes; (void)n_in; (void)ws_size;
  const float* x          = (const float*)d_in[0];
  const int*   state1     = (const int*)d_in[1];
  const float* log_scale1 = (const float*)d_in[2];
  const float* bias1      = (const float*)d_in[3];
  const int*   state2     = (const int*)d_in[4];
  const float* log_scale2 = (const float*)d_in[5];
  const float* bias2      = (const float*)d_in[6];
  const float* w_out      = (const float*)d_in[7];
  const float* b_out      = (const float*)d_in[8];
  float* out = (float*)d_out;

  char* ws = (char*)d_ws;
  unsigned short* xb  = (unsigned short*)ws; ws += (size_t)BATCH * IN_DIM * 2;  // 32 MB
  unsigned short* s1b = (unsigned short*)ws; ws += (size_t)HDIM * IN_DIM * 2;   // 8 MB
  unsigned short* s2b = (unsigned short*)ws; ws += (size_t)HDIM * HDIM * 2;     // 32 MB
  unsigned short* h1  = (unsigned short*)ws; ws += (size_t)BATCH * HDIM * 2;    // 128 MB
  float* scale1 = (float*)ws; ws += HDIM * sizeof(float);
  float* scale2 = (float*)ws; ws += HDIM * sizeof(float);

  cvt_f32_bf16_kernel<<<(BATCH * IN_DIM / 4 + 255) / 256, 256, 0, stream>>>(x, xb, BATCH * IN_DIM / 4);
  cvt_i32_bf16_kernel<<<(HDIM * IN_DIM / 4 + 255) / 256, 256, 0, stream>>>(state1, s1b, HDIM * IN_DIM / 4);
  cvt_i32_bf16_kernel<<<(HDIM * HDIM / 4 + 255) / 256, 256, 0, stream>>>(state2, s2b, HDIM * HDIM / 4);
  scale_kernel<<<(HDIM + 255) / 256, 256, 0, stream>>>(log_scale1, scale1, HDIM);
  scale_kernel<<<(HDIM + 255) / 256, 256, 0, stream>>>(log_scale2, scale2, HDIM);
  init_out_kernel<<<(out_size + 255) / 256, 256, 0, stream>>>(out, b_out, out_size);

  dim3 grid(HDIM / 128, BATCH / 128);  // 32 x 128
  gemm_kernel<IN_DIM, false><<<grid, 256, 0, stream>>>(xb, s1b, scale1, bias1, h1, nullptr, nullptr);
  gemm_kernel<HDIM, true><<<grid, 256, 0, stream>>>(h1, s2b, scale2, bias2, nullptr, w_out, out);
}

// Round 2
// 896.668 us; speedup vs baseline: 1.0282x; 1.0282x over previous
//
#include <hip/hip_runtime.h>
#include <stdint.h>

#define BATCH 16384
#define IN_DIM 1024
#define HDIM 4096

typedef __bf16 bf16x8 __attribute__((ext_vector_type(8)));
typedef short short8 __attribute__((ext_vector_type(8)));
typedef float f32x16 __attribute__((ext_vector_type(16)));

typedef const __attribute__((address_space(1))) void* gas_ptr;
typedef __attribute__((address_space(3))) void* las_ptr;

__device__ __forceinline__ unsigned short f2bf(float f) {
  uint32_t u = __builtin_bit_cast(uint32_t, f);
  u += 0x7fffu + ((u >> 16) & 1u);
  return (unsigned short)(u >> 16);
}

__device__ __forceinline__ void async_copy16(const void* g, void* l) {
  __builtin_amdgcn_global_load_lds((gas_ptr)g, (las_ptr)l, 16, 0, 0);
}

// ---------------- small prep kernels ----------------

__global__ void cvt_f32_bf16_kernel(const float* __restrict__ in,
                                    unsigned short* __restrict__ out, int n4) {
  int i = blockIdx.x * blockDim.x + threadIdx.x;
  if (i < n4) {
    const float4 v = ((const float4*)in)[i];
    ushort4 o;
    o.x = f2bf(v.x); o.y = f2bf(v.y); o.z = f2bf(v.z); o.w = f2bf(v.w);
    ((ushort4*)out)[i] = o;
  }
}

__global__ void cvt_i32_bf16_kernel(const int* __restrict__ in,
                                    unsigned short* __restrict__ out, int n4) {
  int i = blockIdx.x * blockDim.x + threadIdx.x;
  if (i < n4) {
    const int4 v = ((const int4*)in)[i];
    ushort4 o;
    o.x = f2bf((float)v.x); o.y = f2bf((float)v.y);
    o.z = f2bf((float)v.z); o.w = f2bf((float)v.w);
    ((ushort4*)out)[i] = o;
  }
}

__global__ void scale_kernel(const float* __restrict__ ls, float* __restrict__ s, int n) {
  int i = blockIdx.x * blockDim.x + threadIdx.x;
  if (i < n) {
    float l = ls[i];
    float sp = (l > 20.0f) ? l : log1pf(expf(l));
    s[i] = fmaxf(sp, 1e-4f);
  }
}

__global__ void init_out_kernel(float* __restrict__ out, const float* __restrict__ b_out, int n) {
  int i = blockIdx.x * blockDim.x + threadIdx.x;
  if (i < n) out[i] = b_out[0];
}

// ---------------- MFMA GEMM: C[m,n] = sum_k A[m,k]*B[n,k] ----------------
// A: [M][K] bf16 row-major, B: [N][K] bf16 row-major (B^T-input layout).
// 256x128 block tile, 4 waves (2x2), each wave 128x64 via 4x2 of
// mfma_f32_32x32x16_bf16 (2x MACs/operand-byte vs 16x16x32 -> LDS pipe no
// longer critical; MFMA becomes the bottleneck).
// LDS chunk swizzle: 16B chunk c of row r stored at position c ^ ((r>>1)&3)
// -> read pattern hits all 8 bank-groups with exactly 4 lanes each
// (conflict-free minimum; round-1 swizzle left 4 cyc/instr of conflicts).
// Epilogue: v = clip(acc*scale[col]+bias[col], -1, 1).
//   FUSE=false: store v as bf16 into Hout[M][HDIM].
//   FUSE=true : out[row] += sum_col v * w_out[col] (32-lane shuffle reduce + atomicAdd)

template <int K, bool FUSE>
__global__ __launch_bounds__(256, 2)
void gemm_kernel(const unsigned short* __restrict__ A,
                 const unsigned short* __restrict__ B,
                 const float* __restrict__ scale,
                 const float* __restrict__ bias,
                 unsigned short* __restrict__ Hout,
                 const float* __restrict__ w_out,
                 float* __restrict__ out) {
  __shared__ unsigned short As[256 * 32];  // 16 KB
  __shared__ unsigned short Bs[128 * 32];  //  8 KB

  const int tid = threadIdx.x;
  const int wave = tid >> 6;
  const int lane = tid & 63;
  const int r31 = lane & 31;
  const int half = lane >> 5;
  const int wm = wave >> 1;   // 0..1 : 128-row slice
  const int wn = wave & 1;    // 0..1 : 64-col slice
  const int row0 = blockIdx.y * 256;
  const int col0 = blockIdx.x * 128;

  f32x16 acc[4][2];
#pragma unroll
  for (int i = 0; i < 4; ++i)
#pragma unroll
    for (int j = 0; j < 2; ++j)
#pragma unroll
      for (int r = 0; r < 16; ++r) acc[i][j][r] = 0.0f;

  const unsigned short* Ab = A + (size_t)row0 * K;
  const unsigned short* Bb = B + (size_t)col0 * K;

  for (int k0 = 0; k0 < K; k0 += 32) {
    __syncthreads();
    // Stage A (256 rows x 32 bf16 = 1024 chunks of 16 B) in 4 rounds,
    // B (512 chunks) in 2 rounds. LDS position p holds global chunk
    // (row = p>>2, chunk = (p&3) ^ ((row>>1)&3)).
#pragma unroll
    for (int rd = 0; rd < 4; ++rd) {
      const int p = rd * 256 + tid;
      const int r = p >> 2;
      const int c = (p & 3) ^ ((r >> 1) & 3);
      async_copy16(Ab + (size_t)r * K + k0 + c * 8, &As[(rd * 256 + wave * 64) * 8]);
    }
#pragma unroll
    for (int rd = 0; rd < 2; ++rd) {
      const int p = rd * 256 + tid;
      const int r = p >> 2;
      const int c = (p & 3) ^ ((r >> 1) & 3);
      async_copy16(Bb + (size_t)r * K + k0 + c * 8, &Bs[(rd * 256 + wave * 64) * 8]);
    }
    __syncthreads();

    // Two k-steps of 16. A-operand 32x32x16: lane holds row=lane&31,
    // k = (lane>>5)*8 + j (8 contiguous) -> chunk index s*2 + half.
#pragma unroll
    for (int s = 0; s < 2; ++s) {
      const int c = s * 2 + half;
      bf16x8 aF[4], bF[2];
#pragma unroll
      for (int i = 0; i < 4; ++i) {
        const int ar = wm * 128 + i * 32 + r31;
        const int cp = c ^ ((ar >> 1) & 3);
        aF[i] = __builtin_bit_cast(bf16x8, *(const short8*)&As[ar * 32 + cp * 8]);
      }
#pragma unroll
      for (int j = 0; j < 2; ++j) {
        const int br = wn * 64 + j * 32 + r31;
        const int cp = c ^ ((br >> 1) & 3);
        bF[j] = __builtin_bit_cast(bf16x8, *(const short8*)&Bs[br * 32 + cp * 8]);
      }
#pragma unroll
      for (int i = 0; i < 4; ++i)
#pragma unroll
        for (int j = 0; j < 2; ++j)
          acc[i][j] = __builtin_amdgcn_mfma_f32_32x32x16_bf16(aF[i], bF[j], acc[i][j], 0, 0, 0);
    }
  }

  // Epilogue. C/D layout (32x32): col = lane&31,
  // row = (reg&3) + 8*(reg>>2) + 4*(lane>>5).
  if constexpr (!FUSE) {
#pragma unroll
    for (int j = 0; j < 2; ++j) {
      const int col = col0 + wn * 64 + j * 32 + r31;
      const float sc = scale[col];
      const float bs = bias[col];
#pragma unroll
      for (int i = 0; i < 4; ++i) {
        const int rbase = row0 + wm * 128 + i * 32 + 4 * half;
#pragma unroll
        for (int r = 0; r < 16; ++r) {
          const int row = rbase + (r & 3) + 8 * (r >> 2);
          float v = fminf(fmaxf(acc[i][j][r] * sc + bs, -1.0f), 1.0f);
          Hout[(size_t)row * HDIM + col] = f2bf(v);
        }
      }
    }
  } else {
#pragma unroll
    for (int i = 0; i < 4; ++i) {
      float rs[16];
#pragma unroll
      for (int r = 0; r < 16; ++r) rs[r] = 0.0f;
#pragma unroll
      for (int j = 0; j < 2; ++j) {
        const int col = col0 + wn * 64 + j * 32 + r31;
        const float sc = scale[col];
        const float bs = bias[col];
        const float w = w_out[col];
#pragma unroll
        for (int r = 0; r < 16; ++r) {
          float v = fminf(fmaxf(acc[i][j][r] * sc + bs, -1.0f), 1.0f);
          rs[r] += v * w;
        }
      }
      // reduce over the 32 lanes (r31) sharing each row
#pragma unroll
      for (int off = 1; off < 32; off <<= 1)
#pragma unroll
        for (int r = 0; r < 16; ++r)
          rs[r] += __shfl_xor(rs[r], off, 64);
      if (r31 == 0) {
        const int rbase = row0 + wm * 128 + i * 32 + 4 * half;
#pragma unroll
        for (int r = 0; r < 16; ++r)
          atomicAdd(&out[rbase + (r & 3) + 8 * (r >> 2)], rs[r]);
      }
    }
  }
}

// ---------------- launch ----------------

extern "C" void kernel_launch(void* const* d_in, const int* in_sizes, int n_in,
                              void* d_out, int out_size, void* d_ws, size_t ws_size,
                              hipStream_t stream) {
  (void)in_sizes; (void)n_in; (void)ws_size;
  const float* x          = (const float*)d_in[0];
  const int*   state1     = (const int*)d_in[1];
  const float* log_scale1 = (const float*)d_in[2];
  const float* bias1      = (const float*)d_in[3];
  const int*   state2     = (const int*)d_in[4];
  const float* log_scale2 = (const float*)d_in[5];
  const float* bias2      = (const float*)d_in[6];
  const float* w_out      = (const float*)d_in[7];
  const float* b_out      = (const float*)d_in[8];
  float* out = (float*)d_out;

  char* ws = (char*)d_ws;
  unsigned short* xb  = (unsigned short*)ws; ws += (size_t)BATCH * IN_DIM * 2;  // 32 MB
  unsigned short* s1b = (unsigned short*)ws; ws += (size_t)HDIM * IN_DIM * 2;   // 8 MB
  unsigned short* s2b = (unsigned short*)ws; ws += (size_t)HDIM * HDIM * 2;     // 32 MB
  unsigned short* h1  = (unsigned short*)ws; ws += (size_t)BATCH * HDIM * 2;    // 128 MB
  float* scale1 = (float*)ws; ws += HDIM * sizeof(float);
  float* scale2 = (float*)ws; ws += HDIM * sizeof(float);

  cvt_f32_bf16_kernel<<<(BATCH * IN_DIM / 4 + 255) / 256, 256, 0, stream>>>(x, xb, BATCH * IN_DIM / 4);
  cvt_i32_bf16_kernel<<<(HDIM * IN_DIM / 4 + 255) / 256, 256, 0, stream>>>(state1, s1b, HDIM * IN_DIM / 4);
  cvt_i32_bf16_kernel<<<(HDIM * HDIM / 4 + 255) / 256, 256, 0, stream>>>(state2, s2b, HDIM * HDIM / 4);
  scale_kernel<<<(HDIM + 255) / 256, 256, 0, stream>>>(log_scale1, scale1, HDIM);
  scale_kernel<<<(HDIM + 255) / 256, 256, 0, stream>>>(log_scale2, scale2, HDIM);
  init_out_kernel<<<(out_size + 255) / 256, 256, 0, stream>>>(out, b_out, out_size);

  dim3 grid(HDIM / 128, BATCH / 256);  // 32 x 64
  gemm_kernel<IN_DIM, false><<<grid, 256, 0, stream>>>(xb, s1b, scale1, bias1, h1, nullptr, nullptr);
  gemm_kernel<HDIM, true><<<grid, 256, 0, stream>>>(h1, s2b, scale2, bias2, nullptr, w_out, out);
}

// Round 3
// 664.111 us; speedup vs baseline: 1.3882x; 1.3502x over previous
//
#include <hip/hip_runtime.h>
#include <stdint.h>

#define BATCH 16384
#define IN_DIM 1024
#define HDIM 4096

typedef _Float16 f16x8 __attribute__((ext_vector_type(8)));
typedef short short8 __attribute__((ext_vector_type(8)));
typedef float f32x16 __attribute__((ext_vector_type(16)));
typedef int i32x4 __attribute__((ext_vector_type(4)));
typedef int i32x16 __attribute__((ext_vector_type(16)));

typedef const __attribute__((address_space(1))) void* gas_ptr;
typedef __attribute__((address_space(3))) void* las_ptr;

__device__ __forceinline__ void async_copy16(const void* g, void* l) {
  __builtin_amdgcn_global_load_lds((gas_ptr)g, (las_ptr)l, 16, 0, 0);
}

// ---------------- small prep kernels ----------------

__global__ void cvt_f32_f16_kernel(const float* __restrict__ in,
                                   unsigned short* __restrict__ out, int n4) {
  int i = blockIdx.x * blockDim.x + threadIdx.x;
  if (i < n4) {
    const float4 v = ((const float4*)in)[i];
    ushort4 o;
    o.x = __builtin_bit_cast(unsigned short, (_Float16)v.x);
    o.y = __builtin_bit_cast(unsigned short, (_Float16)v.y);
    o.z = __builtin_bit_cast(unsigned short, (_Float16)v.z);
    o.w = __builtin_bit_cast(unsigned short, (_Float16)v.w);
    ((ushort4*)out)[i] = o;
  }
}

__global__ void cvt_i32_f16_kernel(const int* __restrict__ in,
                                   unsigned short* __restrict__ out, int n4) {
  int i = blockIdx.x * blockDim.x + threadIdx.x;
  if (i < n4) {
    const int4 v = ((const int4*)in)[i];
    ushort4 o;
    o.x = __builtin_bit_cast(unsigned short, (_Float16)(float)v.x);
    o.y = __builtin_bit_cast(unsigned short, (_Float16)(float)v.y);
    o.z = __builtin_bit_cast(unsigned short, (_Float16)(float)v.z);
    o.w = __builtin_bit_cast(unsigned short, (_Float16)(float)v.w);
    ((ushort4*)out)[i] = o;
  }
}

// state2 int32 {-1,0,1} -> i8, 4-at-a-time packed into one dword store
__global__ void cvt_i32_i8_kernel(const int* __restrict__ in,
                                  unsigned int* __restrict__ out, int n4) {
  int i = blockIdx.x * blockDim.x + threadIdx.x;
  if (i < n4) {
    const int4 v = ((const int4*)in)[i];
    unsigned int p = (v.x & 0xffu) | ((v.y & 0xffu) << 8) |
                     ((v.z & 0xffu) << 16) | ((v.w & 0xffu) << 24);
    out[i] = p;
  }
}

// s[i] = max(softplus(ls[i]), 1e-4) * mul   (mul = 1 or 1/127 for i8 dequant)
__global__ void scale_kernel(const float* __restrict__ ls, float* __restrict__ s,
                             float mul, int n) {
  int i = blockIdx.x * blockDim.x + threadIdx.x;
  if (i < n) {
    float l = ls[i];
    float sp = (l > 20.0f) ? l : log1pf(expf(l));
    s[i] = fmaxf(sp, 1e-4f) * mul;
  }
}

__global__ void init_out_kernel(float* __restrict__ out, const float* __restrict__ b_out, int n) {
  int i = blockIdx.x * blockDim.x + threadIdx.x;
  if (i < n) out[i] = b_out[0];
}

// ---------------- GEMM1 (f16 MFMA): h1_i8 = round(127*clip(x @ W1^T*s + b)) ----
// A: x_f16 [M][1024], B: state1_f16 [4096][1024] (B^T layout).
// 256x128 tile, 4 waves (2x2), wave = 128x64 via 4x2 mfma_f32_32x32x16_f16.
// Epilogue quantizes hardtanh output to i8 (exact ternary W2 + exact i32
// accum in GEMM2 make i8 h1 the only quantization noise there).

__global__ __launch_bounds__(256, 2)
void gemm1_kernel(const unsigned short* __restrict__ A,
                  const unsigned short* __restrict__ B,
                  const float* __restrict__ scale,
                  const float* __restrict__ bias,
                  signed char* __restrict__ Hout) {
  constexpr int K = IN_DIM;
  __shared__ __align__(16) unsigned short As[256 * 32];  // 16 KB
  __shared__ __align__(16) unsigned short Bs[128 * 32];  //  8 KB

  const int tid = threadIdx.x;
  const int wave = tid >> 6;
  const int lane = tid & 63;
  const int r31 = lane & 31;
  const int half = lane >> 5;
  const int wm = wave >> 1;
  const int wn = wave & 1;
  const int row0 = blockIdx.y * 256;
  const int col0 = blockIdx.x * 128;

  f32x16 acc[4][2];
#pragma unroll
  for (int i = 0; i < 4; ++i)
#pragma unroll
    for (int j = 0; j < 2; ++j)
#pragma unroll
      for (int r = 0; r < 16; ++r) acc[i][j][r] = 0.0f;

  const unsigned short* Ab = A + (size_t)row0 * K;
  const unsigned short* Bb = B + (size_t)col0 * K;

  for (int k0 = 0; k0 < K; k0 += 32) {
    __syncthreads();
    // LDS slot p holds global 16B chunk (row=p>>2, chunk=(p&3)^((row>>1)&3))
#pragma unroll
    for (int rd = 0; rd < 4; ++rd) {
      const int p = rd * 256 + tid;
      const int r = p >> 2;
      const int c = (p & 3) ^ ((r >> 1) & 3);
      async_copy16(Ab + (size_t)r * K + k0 + c * 8, &As[(rd * 256 + wave * 64) * 8]);
    }
#pragma unroll
    for (int rd = 0; rd < 2; ++rd) {
      const int p = rd * 256 + tid;
      const int r = p >> 2;
      const int c = (p & 3) ^ ((r >> 1) & 3);
      async_copy16(Bb + (size_t)r * K + k0 + c * 8, &Bs[(rd * 256 + wave * 64) * 8]);
    }
    __syncthreads();

#pragma unroll
    for (int s = 0; s < 2; ++s) {
      const int c = s * 2 + half;
      f16x8 aF[4], bF[2];
#pragma unroll
      for (int i = 0; i < 4; ++i) {
        const int ar = wm * 128 + i * 32 + r31;
        const int cp = c ^ ((ar >> 1) & 3);
        aF[i] = __builtin_bit_cast(f16x8, *(const short8*)&As[ar * 32 + cp * 8]);
      }
#pragma unroll
      for (int j = 0; j < 2; ++j) {
        const int br = wn * 64 + j * 32 + r31;
        const int cp = c ^ ((br >> 1) & 3);
        bF[j] = __builtin_bit_cast(f16x8, *(const short8*)&Bs[br * 32 + cp * 8]);
      }
#pragma unroll
      for (int i = 0; i < 4; ++i)
#pragma unroll
        for (int j = 0; j < 2; ++j)
          acc[i][j] = __builtin_amdgcn_mfma_f32_32x32x16_f16(aF[i], bF[j], acc[i][j], 0, 0, 0);
    }
  }

  // C/D 32x32 layout: col = lane&31, row = (reg&3)+8*(reg>>2)+4*(lane>>5)
#pragma unroll
  for (int j = 0; j < 2; ++j) {
    const int col = col0 + wn * 64 + j * 32 + r31;
    const float sc = scale[col];
    const float bs = bias[col];
#pragma unroll
    for (int i = 0; i < 4; ++i) {
      const int rbase = row0 + wm * 128 + i * 32 + 4 * half;
#pragma unroll
      for (int r = 0; r < 16; ++r) {
        const int row = rbase + (r & 3) + 8 * (r >> 2);
        float v = fminf(fmaxf(acc[i][j][r] * sc + bs, -1.0f), 1.0f);
        Hout[(size_t)row * HDIM + col] = (signed char)(int)rintf(v * 127.0f);
      }
    }
  }
}

// ---------------- GEMM2 (i8 MFMA, fused head) ----------------
// A: h1_i8 [M][4096], B: state2_i8 [4096][4096] (B^T layout, exact ternary).
// Same 256x128 / 4-wave structure, but mfma_i32_32x32x32_i8: K=64 per
// staging iter at the SAME staged-byte volume as the bf16 K=32 version ->
// 2x MFMA work per byte (the m145/m148 lever past the ~37% plateau), plus
// exact i32 accumulation. Epilogue fuses the OUT_DIM=1 head.

__global__ __launch_bounds__(256, 2)
void gemm2_kernel(const signed char* __restrict__ A,
                  const signed char* __restrict__ B,
                  const float* __restrict__ scale,   // softplus/127 (dequant fused)
                  const float* __restrict__ bias,
                  const float* __restrict__ w_out,
                  float* __restrict__ out) {
  constexpr int K = HDIM;
  __shared__ __align__(16) signed char As[256 * 64];  // 16 KB
  __shared__ __align__(16) signed char Bs[128 * 64];  //  8 KB

  const int tid = threadIdx.x;
  const int wave = tid >> 6;
  const int lane = tid & 63;
  const int r31 = lane & 31;
  const int half = lane >> 5;
  const int wm = wave >> 1;
  const int wn = wave & 1;
  const int row0 = blockIdx.y * 256;
  const int col0 = blockIdx.x * 128;

  i32x16 acc[4][2];
#pragma unroll
  for (int i = 0; i < 4; ++i)
#pragma unroll
    for (int j = 0; j < 2; ++j)
#pragma unroll
      for (int r = 0; r < 16; ++r) acc[i][j][r] = 0;

  const signed char* Ab = A + (size_t)row0 * K;
  const signed char* Bb = B + (size_t)col0 * K;

  for (int k0 = 0; k0 < K; k0 += 64) {
    __syncthreads();
    // 16B chunk = 16 i8; 4 chunks per row of 64. Same slot swizzle as GEMM1.
#pragma unroll
    for (int rd = 0; rd < 4; ++rd) {
      const int p = rd * 256 + tid;
      const int r = p >> 2;
      const int c = (p & 3) ^ ((r >> 1) & 3);
      async_copy16(Ab + (size_t)r * K + k0 + c * 16, &As[(rd * 256 + wave * 64) * 16]);
    }
#pragma unroll
    for (int rd = 0; rd < 2; ++rd) {
      const int p = rd * 256 + tid;
      const int r = p >> 2;
      const int c = (p & 3) ^ ((r >> 1) & 3);
      async_copy16(Bb + (size_t)r * K + k0 + c * 16, &Bs[(rd * 256 + wave * 64) * 16]);
    }
    __syncthreads();

    // Two k-steps of 32. A-operand (extension of verified 32x32x16 bf16
    // mapping): row = lane&31, k = (lane>>5)*16 + j, 16 contiguous i8 = one
    // 16B chunk at index s*2 + half.
#pragma unroll
    for (int s = 0; s < 2; ++s) {
      const int c = s * 2 + half;
      i32x4 aF[4], bF[2];
#pragma unroll
      for (int i = 0; i < 4; ++i) {
        const int ar = wm * 128 + i * 32 + r31;
        const int cp = c ^ ((ar >> 1) & 3);
        aF[i] = *(const i32x4*)&As[ar * 64 + cp * 16];
      }
#pragma unroll
      for (int j = 0; j < 2; ++j) {
        const int br = wn * 64 + j * 32 + r31;
        const int cp = c ^ ((br >> 1) & 3);
        bF[j] = *(const i32x4*)&Bs[br * 64 + cp * 16];
      }
#pragma unroll
      for (int i = 0; i < 4; ++i)
#pragma unroll
        for (int j = 0; j < 2; ++j)
          acc[i][j] = __builtin_amdgcn_mfma_i32_32x32x32_i8(aF[i], bF[j], acc[i][j], 0, 0, 0);
    }
  }

  // Fused head: out[row] += sum_col clip(acc*sc+bs)*w_out[col]
#pragma unroll
  for (int i = 0; i < 4; ++i) {
    float rs[16];
#pragma unroll
    for (int r = 0; r < 16; ++r) rs[r] = 0.0f;
#pragma unroll
    for (int j = 0; j < 2; ++j) {
      const int col = col0 + wn * 64 + j * 32 + r31;
      const float sc = scale[col];
      const float bs = bias[col];
      const float w = w_out[col];
#pragma unroll
      for (int r = 0; r < 16; ++r) {
        float v = fminf(fmaxf((float)acc[i][j][r] * sc + bs, -1.0f), 1.0f);
        rs[r] += v * w;
      }
    }
#pragma unroll
    for (int off = 1; off < 32; off <<= 1)
#pragma unroll
      for (int r = 0; r < 16; ++r)
        rs[r] += __shfl_xor(rs[r], off, 64);
    if (r31 == 0) {
      const int rbase = row0 + wm * 128 + i * 32 + 4 * half;
#pragma unroll
      for (int r = 0; r < 16; ++r)
        atomicAdd(&out[rbase + (r & 3) + 8 * (r >> 2)], rs[r]);
    }
  }
}

// ---------------- launch ----------------

extern "C" void kernel_launch(void* const* d_in, const int* in_sizes, int n_in,
                              void* d_out, int out_size, void* d_ws, size_t ws_size,
                              hipStream_t stream) {
  (void)in_sizes; (void)n_in; (void)ws_size;
  const float* x          = (const float*)d_in[0];
  const int*   state1     = (const int*)d_in[1];
  const float* log_scale1 = (const float*)d_in[2];
  const float* bias1      = (const float*)d_in[3];
  const int*   state2     = (const int*)d_in[4];
  const float* log_scale2 = (const float*)d_in[5];
  const float* bias2      = (const float*)d_in[6];
  const float* w_out      = (const float*)d_in[7];
  const float* b_out      = (const float*)d_in[8];
  float* out = (float*)d_out;

  char* ws = (char*)d_ws;
  unsigned short* xh  = (unsigned short*)ws; ws += (size_t)BATCH * IN_DIM * 2;  // 32 MB
  unsigned short* s1h = (unsigned short*)ws; ws += (size_t)HDIM * IN_DIM * 2;   // 8 MB
  signed char*    s2q = (signed char*)ws;    ws += (size_t)HDIM * HDIM;         // 16 MB
  signed char*    h1q = (signed char*)ws;    ws += (size_t)BATCH * HDIM;        // 64 MB
  float* scale1 = (float*)ws; ws += HDIM * sizeof(float);
  float* scale2 = (float*)ws; ws += HDIM * sizeof(float);

  cvt_f32_f16_kernel<<<(BATCH * IN_DIM / 4 + 255) / 256, 256, 0, stream>>>(x, xh, BATCH * IN_DIM / 4);
  cvt_i32_f16_kernel<<<(HDIM * IN_DIM / 4 + 255) / 256, 256, 0, stream>>>(state1, s1h, HDIM * IN_DIM / 4);
  cvt_i32_i8_kernel<<<(HDIM * HDIM / 4 + 255) / 256, 256, 0, stream>>>(state2, (unsigned int*)s2q, HDIM * HDIM / 4);
  scale_kernel<<<(HDIM + 255) / 256, 256, 0, stream>>>(log_scale1, scale1, 1.0f, HDIM);
  scale_kernel<<<(HDIM + 255) / 256, 256, 0, stream>>>(log_scale2, scale2, 1.0f / 127.0f, HDIM);
  init_out_kernel<<<(out_size + 255) / 256, 256, 0, stream>>>(out, b_out, out_size);

  dim3 grid(HDIM / 128, BATCH / 256);  // 32 x 64
  gemm1_kernel<<<grid, 256, 0, stream>>>(xh, s1h, scale1, bias1, h1q);
  gemm2_kernel<<<grid, 256, 0, stream>>>(h1q, s2q, scale2, bias2, w_out, out);
}

// Round 6
// 616.006 us; speedup vs baseline: 1.4966x; 1.0781x over previous
//
#include <hip/hip_runtime.h>
#include <stdint.h>

#define BATCH 16384
#define IN_DIM 1024
#define HDIM 4096

typedef _Float16 f16x8 __attribute__((ext_vector_type(8)));
typedef short short8 __attribute__((ext_vector_type(8)));
typedef float f32x16 __attribute__((ext_vector_type(16)));
typedef int i32x4 __attribute__((ext_vector_type(4)));
typedef int i32x16 __attribute__((ext_vector_type(16)));

typedef const __attribute__((address_space(1))) void* gas_ptr;
typedef __attribute__((address_space(3))) void* las_ptr;

__device__ __forceinline__ void async_copy16(const void* g, void* l) {
  __builtin_amdgcn_global_load_lds((gas_ptr)g, (las_ptr)l, 16, 0, 0);
}

// ---------------- prep kernels ----------------

// x float -> f16, 4 at a time
__global__ void cvt_x_f16_kernel(const float* __restrict__ in,
                                 unsigned short* __restrict__ out, int n4) {
  int i = blockIdx.x * blockDim.x + threadIdx.x;
  if (i < n4) {
    const float4 v = ((const float4*)in)[i];
    ushort4 o;
    o.x = __builtin_bit_cast(unsigned short, (_Float16)v.x);
    o.y = __builtin_bit_cast(unsigned short, (_Float16)v.y);
    o.z = __builtin_bit_cast(unsigned short, (_Float16)v.z);
    o.w = __builtin_bit_cast(unsigned short, (_Float16)v.w);
    ((ushort4*)out)[i] = o;
  }
}

// state1 -> f16 and state2 -> packed i8 in one launch
__global__ void cvt_s_kernel(const int* __restrict__ s1, unsigned short* __restrict__ o1, int n1_4,
                             const int* __restrict__ s2, unsigned int* __restrict__ o2, int n2_4) {
  int i = blockIdx.x * blockDim.x + threadIdx.x;
  if (i < n1_4) {
    const int4 v = ((const int4*)s1)[i];
    ushort4 o;
    o.x = __builtin_bit_cast(unsigned short, (_Float16)(float)v.x);
    o.y = __builtin_bit_cast(unsigned short, (_Float16)(float)v.y);
    o.z = __builtin_bit_cast(unsigned short, (_Float16)(float)v.z);
    o.w = __builtin_bit_cast(unsigned short, (_Float16)(float)v.w);
    ((ushort4*)o1)[i] = o;
  } else if (i < n1_4 + n2_4) {
    const int j = i - n1_4;
    const int4 v = ((const int4*)s2)[j];
    o2[j] = (v.x & 0xffu) | ((v.y & 0xffu) << 8) | ((v.z & 0xffu) << 16) | ((v.w & 0xffu) << 24);
  }
}

// scale1 = max(softplus(ls1),1e-4); scale2 = max(softplus(ls2),1e-4)/127
// (h1-i8 dequant fused); plus out[i] = b_out[0] for ALL out_size rows.
// ROUND 4/5 BUG (both failed on this, NOT on numerics): only out[0] was
// initialized; rows 1..16383 missed the b_out bias (|b_out|~1/64 = the
// observed 1.3e-2 absmax). Launch must cover max(out_size, 2*HDIM) threads.
__global__ void scales_init_kernel(const float* __restrict__ ls1, float* __restrict__ s1,
                                   const float* __restrict__ ls2, float* __restrict__ s2,
                                   const float* __restrict__ b_out, float* __restrict__ out,
                                   int out_n) {
  int i = blockIdx.x * blockDim.x + threadIdx.x;
  if (i < out_n) out[i] = b_out[0];
  if (i < HDIM) {
    float l = ls1[i];
    float sp = (l > 20.0f) ? l : log1pf(expf(l));
    s1[i] = fmaxf(sp, 1e-4f);
  } else if (i < 2 * HDIM) {
    float l = ls2[i - HDIM];
    float sp = (l > 20.0f) ? l : log1pf(expf(l));
    s2[i - HDIM] = fmaxf(sp, 1e-4f) * (1.0f / 127.0f);
  }
}

// ---------------- GEMM1 (f16 MFMA, BK=64): h1_i8 = rint(127*clip(...)) ------
// A: x_f16 [M][1024], B: state1_f16 [4096][1024] (B^T layout).
// 256x128 tile, BK=64 (48 KB LDS/iter), 4 waves (2x2), wave = 128x64 via
// 4x2 mfma_f32_32x32x16_f16, 4 k-steps/iter. LDS: 16B chunk c of row r at
// slot c^(r&7). Epilogue quantizes hardtanh output to i8 for GEMM2.

__global__ __launch_bounds__(256, 2)
void gemm1_kernel(const unsigned short* __restrict__ A,
                  const unsigned short* __restrict__ B,
                  const float* __restrict__ scale,
                  const float* __restrict__ bias,
                  signed char* __restrict__ Hout) {
  constexpr int K = IN_DIM;
  __shared__ __align__(16) unsigned short As[256 * 64];  // 32 KB
  __shared__ __align__(16) unsigned short Bs[128 * 64];  // 16 KB

  const int tid = threadIdx.x;
  const int wave = tid >> 6;
  const int lane = tid & 63;
  const int r31 = lane & 31;
  const int half = lane >> 5;
  const int wm = wave >> 1;
  const int wn = wave & 1;
  const int row0 = blockIdx.y * 256;
  const int col0 = blockIdx.x * 128;

  f32x16 acc[4][2];
#pragma unroll
  for (int i = 0; i < 4; ++i)
#pragma unroll
    for (int j = 0; j < 2; ++j)
#pragma unroll
      for (int r = 0; r < 16; ++r) acc[i][j][r] = 0.0f;

  const unsigned short* Ab = A + (size_t)row0 * K;
  const unsigned short* Bb = B + (size_t)col0 * K;

  for (int k0 = 0; k0 < K; k0 += 64) {
    __syncthreads();
    // A: 256 rows x 128 B = 2048 chunks of 16 B (8 f16), 8 rounds.
    // LDS slot p holds global chunk (row=p>>3, chunk=(p&7)^(row&7)).
#pragma unroll
    for (int rd = 0; rd < 8; ++rd) {
      const int p = rd * 256 + tid;
      const int r = p >> 3;
      const int c = (p & 7) ^ (r & 7);
      async_copy16(Ab + (size_t)r * K + k0 + c * 8, &As[(rd * 256 + wave * 64) * 8]);
    }
    // B: 1024 chunks, 4 rounds.
#pragma unroll
    for (int rd = 0; rd < 4; ++rd) {
      const int p = rd * 256 + tid;
      const int r = p >> 3;
      const int c = (p & 7) ^ (r & 7);
      async_copy16(Bb + (size_t)r * K + k0 + c * 8, &Bs[(rd * 256 + wave * 64) * 8]);
    }
    __syncthreads();

    // 4 k-steps of 16. Operand: row = lane&31, k = s*16 + half*8 + j
    // -> chunk c = s*2 + half.
#pragma unroll
    for (int s = 0; s < 4; ++s) {
      const int c = s * 2 + half;
      f16x8 aF[4], bF[2];
#pragma unroll
      for (int i = 0; i < 4; ++i) {
        const int ar = wm * 128 + i * 32 + r31;
        const int cp = c ^ (ar & 7);
        aF[i] = __builtin_bit_cast(f16x8, *(const short8*)&As[ar * 64 + cp * 8]);
      }
#pragma unroll
      for (int j = 0; j < 2; ++j) {
        const int br = wn * 64 + j * 32 + r31;
        const int cp = c ^ (br & 7);
        bF[j] = __builtin_bit_cast(f16x8, *(const short8*)&Bs[br * 64 + cp * 8]);
      }
#pragma unroll
      for (int i = 0; i < 4; ++i)
#pragma unroll
        for (int j = 0; j < 2; ++j)
          acc[i][j] = __builtin_amdgcn_mfma_f32_32x32x16_f16(aF[i], bF[j], acc[i][j], 0, 0, 0);
    }
  }

  // C/D 32x32 layout: col = lane&31, row = (reg&3)+8*(reg>>2)+4*(lane>>5)
#pragma unroll
  for (int j = 0; j < 2; ++j) {
    const int col = col0 + wn * 64 + j * 32 + r31;
    const float sc = scale[col];
    const float bs = bias[col];
#pragma unroll
    for (int i = 0; i < 4; ++i) {
      const int rbase = row0 + wm * 128 + i * 32 + 4 * half;
#pragma unroll
      for (int r = 0; r < 16; ++r) {
        const int row = rbase + (r & 3) + 8 * (r >> 2);
        float v = fminf(fmaxf(acc[i][j][r] * sc + bs, -1.0f), 1.0f);
        Hout[(size_t)row * HDIM + col] = (signed char)(int)rintf(v * 127.0f);
      }
    }
  }
}

// ---------------- GEMM2 (i8 MFMA, BK=128, fused head) ----------------
// A: h1_i8 [M][4096], B: state2_i8 [4096][4096] (exact ternary).
// Same staging byte-structure as GEMM1 (48 KB/iter), mfma_i32_32x32x32_i8,
// exact i32 accumulation. Epilogue fuses the OUT_DIM=1 head.

__global__ __launch_bounds__(256, 2)
void gemm2_kernel(const signed char* __restrict__ A,
                  const signed char* __restrict__ B,
                  const float* __restrict__ scale,   // softplus/127
                  const float* __restrict__ bias,
                  const float* __restrict__ w_out,
                  float* __restrict__ out) {
  constexpr int K = HDIM;
  __shared__ __align__(16) signed char As[256 * 128];  // 32 KB
  __shared__ __align__(16) signed char Bs[128 * 128];  // 16 KB

  const int tid = threadIdx.x;
  const int wave = tid >> 6;
  const int lane = tid & 63;
  const int r31 = lane & 31;
  const int half = lane >> 5;
  const int wm = wave >> 1;
  const int wn = wave & 1;
  const int row0 = blockIdx.y * 256;
  const int col0 = blockIdx.x * 128;

  i32x16 acc[4][2];
#pragma unroll
  for (int i = 0; i < 4; ++i)
#pragma unroll
    for (int j = 0; j < 2; ++j)
#pragma unroll
      for (int r = 0; r < 16; ++r) acc[i][j][r] = 0;

  const signed char* Ab = A + (size_t)row0 * K;
  const signed char* Bb = B + (size_t)col0 * K;

  for (int k0 = 0; k0 < K; k0 += 128) {
    __syncthreads();
#pragma unroll
    for (int rd = 0; rd < 8; ++rd) {
      const int p = rd * 256 + tid;
      const int r = p >> 3;
      const int c = (p & 7) ^ (r & 7);
      async_copy16(Ab + (size_t)r * K + k0 + c * 16, &As[(rd * 256 + wave * 64) * 16]);
    }
#pragma unroll
    for (int rd = 0; rd < 4; ++rd) {
      const int p = rd * 256 + tid;
      const int r = p >> 3;
      const int c = (p & 7) ^ (r & 7);
      async_copy16(Bb + (size_t)r * K + k0 + c * 16, &Bs[(rd * 256 + wave * 64) * 16]);
    }
    __syncthreads();

    // 4 k-steps of 32: row = lane&31, k = s*32 + half*16 + j -> chunk s*2+half
#pragma unroll
    for (int s = 0; s < 4; ++s) {
      const int c = s * 2 + half;
      i32x4 aF[4], bF[2];
#pragma unroll
      for (int i = 0; i < 4; ++i) {
        const int ar = wm * 128 + i * 32 + r31;
        const int cp = c ^ (ar & 7);
        aF[i] = *(const i32x4*)&As[ar * 128 + cp * 16];
      }
#pragma unroll
      for (int j = 0; j < 2; ++j) {
        const int br = wn * 64 + j * 32 + r31;
        const int cp = c ^ (br & 7);
        bF[j] = *(const i32x4*)&Bs[br * 128 + cp * 16];
      }
#pragma unroll
      for (int i = 0; i < 4; ++i)
#pragma unroll
        for (int j = 0; j < 2; ++j)
          acc[i][j] = __builtin_amdgcn_mfma_i32_32x32x32_i8(aF[i], bF[j], acc[i][j], 0, 0, 0);
    }
  }

  // Fused head: out[row] += sum_col clip(acc*sc+bs)*w_out[col]
#pragma unroll
  for (int i = 0; i < 4; ++i) {
    float rs[16];
#pragma unroll
    for (int r = 0; r < 16; ++r) rs[r] = 0.0f;
#pragma unroll
    for (int j = 0; j < 2; ++j) {
      const int col = col0 + wn * 64 + j * 32 + r31;
      const float sc = scale[col];
      const float bs = bias[col];
      const float w = w_out[col];
#pragma unroll
      for (int r = 0; r < 16; ++r) {
        float v = fminf(fmaxf((float)acc[i][j][r] * sc + bs, -1.0f), 1.0f);
        rs[r] += v * w;
      }
    }
#pragma unroll
    for (int off = 1; off < 32; off <<= 1)
#pragma unroll
      for (int r = 0; r < 16; ++r)
        rs[r] += __shfl_xor(rs[r], off, 64);
    if (r31 == 0) {
      const int rbase = row0 + wm * 128 + i * 32 + 4 * half;
#pragma unroll
      for (int r = 0; r < 16; ++r)
        atomicAdd(&out[rbase + (r & 3) + 8 * (r >> 2)], rs[r]);
    }
  }
}

// ---------------- launch ----------------

extern "C" void kernel_launch(void* const* d_in, const int* in_sizes, int n_in,
                              void* d_out, int out_size, void* d_ws, size_t ws_size,
                              hipStream_t stream) {
  (void)in_sizes; (void)n_in; (void)ws_size;
  const float* x          = (const float*)d_in[0];
  const int*   state1     = (const int*)d_in[1];
  const float* log_scale1 = (const float*)d_in[2];
  const float* bias1      = (const float*)d_in[3];
  const int*   state2     = (const int*)d_in[4];
  const float* log_scale2 = (const float*)d_in[5];
  const float* bias2      = (const float*)d_in[6];
  const float* w_out      = (const float*)d_in[7];
  const float* b_out      = (const float*)d_in[8];
  float* out = (float*)d_out;

  char* ws = (char*)d_ws;
  unsigned short* xh  = (unsigned short*)ws; ws += (size_t)BATCH * IN_DIM * 2;  // 32 MB
  unsigned short* s1h = (unsigned short*)ws; ws += (size_t)HDIM * IN_DIM * 2;   // 8 MB
  signed char*    s2q = (signed char*)ws;    ws += (size_t)HDIM * HDIM;         // 16 MB
  signed char*    h1q = (signed char*)ws;    ws += (size_t)BATCH * HDIM;        // 64 MB
  float* scale1 = (float*)ws; ws += HDIM * sizeof(float);
  float* scale2 = (float*)ws; ws += HDIM * sizeof(float);

  const int nx4 = BATCH * IN_DIM / 4;
  const int n1_4 = HDIM * IN_DIM / 4;
  const int n2_4 = HDIM * HDIM / 4;

  cvt_x_f16_kernel<<<(nx4 + 255) / 256, 256, 0, stream>>>(x, xh, nx4);
  cvt_s_kernel<<<(n1_4 + n2_4 + 255) / 256, 256, 0, stream>>>(
      state1, s1h, n1_4, state2, (unsigned int*)s2q, n2_4);
  const int init_n = (out_size > 2 * HDIM) ? out_size : 2 * HDIM;
  scales_init_kernel<<<(init_n + 255) / 256, 256, 0, stream>>>(
      log_scale1, scale1, log_scale2, scale2, b_out, out, out_size);

  dim3 grid(HDIM / 128, BATCH / 256);  // 32 x 64
  gemm1_kernel<<<grid, 256, 0, stream>>>(xh, s1h, scale1, bias1, h1q);
  gemm2_kernel<<<grid, 256, 0, stream>>>(h1q, s2q, scale2, bias2, w_out, out);
}